// Round 5
// baseline (270.184 us; speedup 1.0000x reference)
//
#include <hip/hip_runtime.h>
#include <hip/hip_bf16.h>
#include <stdint.h>
#include <stddef.h>

// HoloLinear factored bf16 MFMA pipeline:
//   resonance[16384,256] = x_f32[16384,2048] @ basis_bf16[256,2048]^T
//   out[16384,8192]      = resonance_bf16 @ wreal_bf16[8192,256]^T
//
// gemm1: (verified r3) fused fp32->bf16, 32x256 tile, BK=64, 32x32x16 MFMA,
//        2-phase dbuf, swizzled LDS.
// gemm2: register-resident, ZERO LDS / ZERO barriers. Operands pre-packed in
//        fragment-ordered tiles (32 rows x 16 k = 1KB, chunk idx = lane) so
//        each frag load is one coalesced dwordx4 at base+lane*16. 3-slot
//        register pipeline, 4 MFMA per k-step, epilogue = verified C/D map.

typedef __bf16 bf16x8 __attribute__((ext_vector_type(8)));
typedef float  f32x4  __attribute__((ext_vector_type(4)));
typedef float  f32x16 __attribute__((ext_vector_type(16)));
typedef unsigned short u16x8 __attribute__((ext_vector_type(8)));

#define M_ROWS 16384
#define K_IN   2048
#define N_OUT  8192
#define N_HARM 256

__device__ inline unsigned short f2bf(float f) {
    union { float f; uint32_t u; } c; c.f = f;
    uint32_t u = c.u;
    uint32_t r = (u + 0x7fffu + ((u >> 16) & 1u)) >> 16;  // RNE
    return (unsigned short)r;
}

__device__ inline bf16x8 cvt8(f32x4 a, f32x4 b) {
    bf16x8 r;
    r[0] = (__bf16)a[0]; r[1] = (__bf16)a[1]; r[2] = (__bf16)a[2]; r[3] = (__bf16)a[3];
    r[4] = (__bf16)b[0]; r[5] = (__bf16)b[1]; r[6] = (__bf16)b[2]; r[7] = (__bf16)b[3];
    return r;
}

#define GLDS(src, dst) \
    __builtin_amdgcn_global_load_lds((const __attribute__((address_space(1))) void*)(src), \
                                     (__attribute__((address_space(3))) void*)(dst), 16, 0, 0)

// ---- fp32 -> bf16 conversion (basis) ----
__global__ __launch_bounds__(256) void cvt_bf16(const float* __restrict__ in,
                                                unsigned short* __restrict__ out) {
    size_t i = ((size_t)blockIdx.x * 256 + threadIdx.x) * 8;
    f32x4 v0 = *(const f32x4*)(in + i);
    f32x4 v1 = *(const f32x4*)(in + i + 4);
    u16x8 o;
    o[0] = f2bf(v0[0]); o[1] = f2bf(v0[1]); o[2] = f2bf(v0[2]); o[3] = f2bf(v0[3]);
    o[4] = f2bf(v1[0]); o[5] = f2bf(v1[1]); o[6] = f2bf(v1[2]); o[7] = f2bf(v1[3]);
    *(u16x8*)(out + i) = o;
}

// ---- w_real = amp * cos(phase) -> bf16, written in B_swz fragment layout ----
// B_swz tile: [otile=o>>5][ktile=h>>4] of 1KB; chunk ch=(o&31)+32*((h>>3)&1),
// elem = h&7.  Thread gid handles o=gid>>5, h0=(gid&31)*8 -> one u16x8 chunk.
__global__ __launch_bounds__(256) void wreal_swz(const float* __restrict__ phase,
                                                 const float* __restrict__ amp,
                                                 unsigned short* __restrict__ out) {
    int gid = blockIdx.x * 256 + threadIdx.x;
    size_t i = (size_t)gid * 8;
    f32x4 p0 = *(const f32x4*)(phase + i);
    f32x4 p1 = *(const f32x4*)(phase + i + 4);
    f32x4 a0 = *(const f32x4*)(amp + i);
    f32x4 a1 = *(const f32x4*)(amp + i + 4);
    u16x8 o;
    o[0] = f2bf(a0[0] * cosf(p0[0])); o[1] = f2bf(a0[1] * cosf(p0[1]));
    o[2] = f2bf(a0[2] * cosf(p0[2])); o[3] = f2bf(a0[3] * cosf(p0[3]));
    o[4] = f2bf(a1[0] * cosf(p1[0])); o[5] = f2bf(a1[1] * cosf(p1[1]));
    o[6] = f2bf(a1[2] * cosf(p1[2])); o[7] = f2bf(a1[3] * cosf(p1[3]));
    int orow = gid >> 5;          // 0..8191
    int j    = gid & 31;          // h0 = j*8
    int kt   = j >> 1;            // h0>>4
    int kh   = j & 1;             // (h0>>3)&1
    int ch   = (orow & 31) + 32 * kh;
    size_t dst = (((size_t)(orow >> 5) * 16 + kt) * 64 + ch) * 8;
    *(u16x8*)(out + dst) = o;
}

// ---- repack rb row-major -> A_swz fragment layout ----
// A_swz tile: [mtile=m>>5][ktile=h>>4], ch=(m&31)+32*((h>>3)&1), elem=h&7.
__global__ __launch_bounds__(256) void repack_rb(const unsigned short* __restrict__ rb,
                                                 unsigned short* __restrict__ out) {
    int gid = blockIdx.x * 256 + threadIdx.x;   // 0..524287
    int m = gid >> 5;
    int j = gid & 31;                            // h0 = j*8
    u16x8 v = *(const u16x8*)(rb + (size_t)m * N_HARM + j * 8);
    int kt = j >> 1;
    int kh = j & 1;
    int ch = (m & 31) + 32 * kh;
    size_t dst = (((size_t)(m >> 5) * 16 + kt) * 64 + ch) * 8;
    *(u16x8*)(out + dst) = v;
}

// ---- gemm1: resonance[M,256] = x_f32[M,2048] @ basis_bf16[256,2048]^T ----
// (unchanged from round 3 — verified)
__global__ __launch_bounds__(256) void gemm1_fused(const float* __restrict__ A,
                                                   const unsigned short* __restrict__ B,
                                                   unsigned short* __restrict__ C) {
    __shared__ float          Asm[2][32 * 64];    // 16 KB
    __shared__ unsigned short Bsm[2][256 * 64];   // 64 KB

    const int tid  = threadIdx.x;
    const int lane = tid & 63;
    const int wv   = tid >> 6;
    const int bm0  = blockIdx.x * 32;

    const float* srcA[2];
#pragma unroll
    for (int q = 0; q < 2; ++q) {
        int L = q * 256 + tid;
        int r = L >> 4, p = L & 15;
        int c = p ^ (r & 15);
        srcA[q] = A + (size_t)(bm0 + r) * K_IN + c * 4;
    }
    const unsigned short* srcB[8];
#pragma unroll
    for (int q = 0; q < 8; ++q) {
        int L = q * 256 + tid;
        int r = L >> 3, p = L & 7;
        int c = p ^ (r & 7);
        srcB[q] = B + (size_t)r * K_IN + c * 8;
    }
    const int dA = wv * 256 + lane * 4;   // floats, + q*1024
    const int dB = wv * 512 + lane * 8;   // shorts, + q*2048

    f32x16 acc[2];
#pragma unroll
    for (int nf = 0; nf < 2; ++nf)
#pragma unroll
        for (int e = 0; e < 16; ++e) acc[nf][e] = 0.f;

    const int r   = lane & 31;
    const int g   = lane >> 5;
    const int r15 = r & 15;
    const int colb = wv * 64;

#pragma unroll
    for (int q = 0; q < 2; ++q) GLDS(srcA[q], &Asm[0][q * 1024 + dA]);
#pragma unroll
    for (int q = 0; q < 8; ++q) GLDS(srcB[q], &Bsm[0][q * 2048 + dB]);
    __syncthreads();

    for (int t = 0; t < 32; ++t) {
        const int buf = t & 1;
        if (t + 1 < 32) {
            const int k0 = (t + 1) * 64;
#pragma unroll
            for (int q = 0; q < 2; ++q) GLDS(srcA[q] + k0, &Asm[buf ^ 1][q * 1024 + dA]);
#pragma unroll
            for (int q = 0; q < 8; ++q) GLDS(srcB[q] + k0, &Bsm[buf ^ 1][q * 2048 + dB]);
        }

        bf16x8 af[4];
#pragma unroll
        for (int ks = 0; ks < 4; ++ks) {
            const int c0 = g * 2 + ks * 4;
            f32x4 lo = *(const f32x4*)&Asm[buf][r * 64 + ((c0)     ^ r15) * 4];
            f32x4 hi = *(const f32x4*)&Asm[buf][r * 64 + ((c0 + 1) ^ r15) * 4];
            af[ks] = cvt8(lo, hi);
        }
#pragma unroll
        for (int nf = 0; nf < 2; ++nf) {
            const int rB = colb + nf * 32 + r;
            const int r7 = rB & 7;
#pragma unroll
            for (int ks = 0; ks < 4; ++ks) {
                const int cB = g + ks * 2;
                bf16x8 bfrag = *(const bf16x8*)&Bsm[buf][rB * 64 + (cB ^ r7) * 8];
                acc[nf] = __builtin_amdgcn_mfma_f32_32x32x16_bf16(af[ks], bfrag, acc[nf], 0, 0, 0);
            }
        }
        __syncthreads();
    }

#pragma unroll
    for (int nf = 0; nf < 2; ++nf)
#pragma unroll
        for (int reg = 0; reg < 16; ++reg) {
            int row = bm0 + (reg & 3) + 8 * (reg >> 2) + 4 * g;
            int col = colb + nf * 32 + r;
            C[(size_t)row * N_HARM + col] = f2bf(acc[nf][reg]);
        }
}

// ---- gemm2_reg: out[M][8192] = rb @ wreal^T, operands in A_swz/B_swz ----
// Block 256 thr = 4 waves (2x2 of 64x64). No LDS, no barriers. Per wave:
// 2 A mtiles + 2 B otiles, 16 k-steps of 32x32x16 MFMA, 3-slot reg pipeline.
__global__ __launch_bounds__(256) void gemm2_reg(const unsigned short* __restrict__ Aswz,
                                                 const unsigned short* __restrict__ Bswz,
                                                 float* __restrict__ Cv) {
    const int tid  = threadIdx.x;
    const int lane = tid & 63;
    const int wv   = tid >> 6;

    // bijective XCD swizzle (8192 blocks, %8==0): XCD x owns an M-stripe
    const int flat = blockIdx.x;
    const int swz  = (flat & 7) * 1024 + (flat >> 3);
    const int bm0  = (swz >> 6) * 128 + (wv >> 1) * 64;
    const int bn0  = (swz & 63) * 128 + (wv & 1) * 64;

    const int mt0 = bm0 >> 5;
    const int nt0 = bn0 >> 5;

    const unsigned short* Ab[2];
    const unsigned short* Bb[2];
#pragma unroll
    for (int i = 0; i < 2; ++i) {
        Ab[i] = Aswz + ((size_t)(mt0 + i) * 16) * 512 + lane * 8;
        Bb[i] = Bswz + ((size_t)(nt0 + i) * 16) * 512 + lane * 8;
    }

    f32x16 acc[2][2];
#pragma unroll
    for (int mi = 0; mi < 2; ++mi)
#pragma unroll
        for (int nj = 0; nj < 2; ++nj)
#pragma unroll
            for (int e = 0; e < 16; ++e) acc[mi][nj][e] = 0.f;

    bf16x8 fa[3][2], fb[3][2];
    // prologue: k-steps 0,1
#pragma unroll
    for (int s = 0; s < 2; ++s)
#pragma unroll
        for (int i = 0; i < 2; ++i) {
            fa[s][i] = *(const bf16x8*)(Ab[i] + s * 512);
            fb[s][i] = *(const bf16x8*)(Bb[i] + s * 512);
        }

#pragma unroll
    for (int ki = 0; ki < 16; ++ki) {
        const int cur = ki % 3;
        if (ki + 2 < 16) {
            const int nx = (ki + 2) % 3;
#pragma unroll
            for (int i = 0; i < 2; ++i) {
                fa[nx][i] = *(const bf16x8*)(Ab[i] + (ki + 2) * 512);
                fb[nx][i] = *(const bf16x8*)(Bb[i] + (ki + 2) * 512);
            }
        }
        acc[0][0] = __builtin_amdgcn_mfma_f32_32x32x16_bf16(fa[cur][0], fb[cur][0], acc[0][0], 0, 0, 0);
        acc[0][1] = __builtin_amdgcn_mfma_f32_32x32x16_bf16(fa[cur][0], fb[cur][1], acc[0][1], 0, 0, 0);
        acc[1][0] = __builtin_amdgcn_mfma_f32_32x32x16_bf16(fa[cur][1], fb[cur][0], acc[1][0], 0, 0, 0);
        acc[1][1] = __builtin_amdgcn_mfma_f32_32x32x16_bf16(fa[cur][1], fb[cur][1], acc[1][1], 0, 0, 0);
    }

    // C/D (32x32): col = lane&31, row = (reg&3) + 8*(reg>>2) + 4*(lane>>5)
    const int r = lane & 31;
    const int g = lane >> 5;
#pragma unroll
    for (int mi = 0; mi < 2; ++mi)
#pragma unroll
        for (int nj = 0; nj < 2; ++nj)
#pragma unroll
            for (int reg = 0; reg < 16; ++reg) {
                int row = bm0 + mi * 32 + (reg & 3) + 8 * (reg >> 2) + 4 * g;
                int col = bn0 + nj * 32 + r;
                Cv[(size_t)row * N_OUT + col] = acc[mi][nj][reg];
            }
}

extern "C" void kernel_launch(void* const* d_in, const int* in_sizes, int n_in,
                              void* d_out, int out_size, void* d_ws, size_t ws_size,
                              hipStream_t stream) {
    const float* x     = (const float*)d_in[0];   // [4,4096,2048]
    const float* basis = (const float*)d_in[1];   // [256,2048]
    const float* phase = (const float*)d_in[2];   // [8192,256]
    const float* amp   = (const float*)d_in[3];   // [8192,256]
    float* out = (float*)d_out;                   // [4,4096,8192] fp32

    char* ws = (char*)d_ws;
    unsigned short* bb    = (unsigned short*)(ws);              // basis bf16: 1 MB
    unsigned short* bswz  = (unsigned short*)(ws + 1048576);    // B_swz:      4 MB
    unsigned short* rb    = (unsigned short*)(ws + 5242880);    // resonance:  8 MB
    unsigned short* aswz  = (unsigned short*)(ws + 13631488);   // A_swz:      8 MB

    cvt_bf16<<<dim3(256), dim3(256), 0, stream>>>(basis, bb);
    wreal_swz<<<dim3(1024), dim3(256), 0, stream>>>(phase, amp, bswz);

    // resonance[16384,256] = x @ bb^T  (fp32 A staged to LDS, fused cvt)
    gemm1_fused<<<dim3(M_ROWS / 32), dim3(256), 0, stream>>>(x, bb, rb);
    // repack rb -> fragment-ordered A_swz (16384*32 chunks / 256)
    repack_rb<<<dim3(2048), dim3(256), 0, stream>>>(rb, aswz);
    // out = rb @ wreal^T, register-resident GEMM (8192 blocks)
    gemm2_reg<<<dim3(8192), dim3(256), 0, stream>>>(aswz, bswz, out);
}

// Round 6
// 209.792 us; speedup vs baseline: 1.2879x; 1.2879x over previous
//
#include <hip/hip_runtime.h>
#include <hip/hip_bf16.h>
#include <stdint.h>
#include <stddef.h>

// HoloLinear factored bf16 MFMA pipeline:
//   resonance[16384,256] = x_f32[16384,2048] @ basis_bf16[256,2048]^T
//   out[16384,8192]      = resonance_bf16 @ wreal_bf16[8192,256]^T
//
// gemm1: (verified r3) fused fp32->bf16, 32x256 tile, BK=64, 32x32x16 MFMA,
//        2-phase dbuf, swizzled LDS.
// gemm2: NEW depth-2 pipelined template: 128x128 tile, BK=32, 4 waves,
//        3 LDS buffers, counted s_waitcnt vmcnt(4) + raw s_barrier (T4 —
//        loads in flight across barriers), packed+XOR-swizzled LDS
//        (4-way residual conflicts), 32x32x16 MFMA.

typedef __bf16 bf16x8 __attribute__((ext_vector_type(8)));
typedef float  f32x4  __attribute__((ext_vector_type(4)));
typedef float  f32x16 __attribute__((ext_vector_type(16)));
typedef unsigned short u16x8 __attribute__((ext_vector_type(8)));

#define M_ROWS 16384
#define K_IN   2048
#define N_OUT  8192
#define N_HARM 256

__device__ inline unsigned short f2bf(float f) {
    union { float f; uint32_t u; } c; c.f = f;
    uint32_t u = c.u;
    uint32_t r = (u + 0x7fffu + ((u >> 16) & 1u)) >> 16;  // RNE
    return (unsigned short)r;
}

__device__ inline bf16x8 cvt8(f32x4 a, f32x4 b) {
    bf16x8 r;
    r[0] = (__bf16)a[0]; r[1] = (__bf16)a[1]; r[2] = (__bf16)a[2]; r[3] = (__bf16)a[3];
    r[4] = (__bf16)b[0]; r[5] = (__bf16)b[1]; r[6] = (__bf16)b[2]; r[7] = (__bf16)b[3];
    return r;
}

#define GLDS(src, dst) \
    __builtin_amdgcn_global_load_lds((const __attribute__((address_space(1))) void*)(src), \
                                     (__attribute__((address_space(3))) void*)(dst), 16, 0, 0)

// ---- fp32 -> bf16 conversion (basis) ----
__global__ __launch_bounds__(256) void cvt_bf16(const float* __restrict__ in,
                                                unsigned short* __restrict__ out) {
    size_t i = ((size_t)blockIdx.x * 256 + threadIdx.x) * 8;
    f32x4 v0 = *(const f32x4*)(in + i);
    f32x4 v1 = *(const f32x4*)(in + i + 4);
    u16x8 o;
    o[0] = f2bf(v0[0]); o[1] = f2bf(v0[1]); o[2] = f2bf(v0[2]); o[3] = f2bf(v0[3]);
    o[4] = f2bf(v1[0]); o[5] = f2bf(v1[1]); o[6] = f2bf(v1[2]); o[7] = f2bf(v1[3]);
    *(u16x8*)(out + i) = o;
}

// ---- w_real = amp * cos(phase) -> bf16 (row-major [8192][256]) ----
__global__ __launch_bounds__(256) void wreal_bf16(const float* __restrict__ phase,
                                                  const float* __restrict__ amp,
                                                  unsigned short* __restrict__ out) {
    size_t i = ((size_t)blockIdx.x * 256 + threadIdx.x) * 8;
    f32x4 p0 = *(const f32x4*)(phase + i);
    f32x4 p1 = *(const f32x4*)(phase + i + 4);
    f32x4 a0 = *(const f32x4*)(amp + i);
    f32x4 a1 = *(const f32x4*)(amp + i + 4);
    u16x8 o;
    o[0] = f2bf(a0[0] * cosf(p0[0])); o[1] = f2bf(a0[1] * cosf(p0[1]));
    o[2] = f2bf(a0[2] * cosf(p0[2])); o[3] = f2bf(a0[3] * cosf(p0[3]));
    o[4] = f2bf(a1[0] * cosf(p1[0])); o[5] = f2bf(a1[1] * cosf(p1[1]));
    o[6] = f2bf(a1[2] * cosf(p1[2])); o[7] = f2bf(a1[3] * cosf(p1[3]));
    *(u16x8*)(out + i) = o;
}

// ---- gemm1: resonance[M,256] = x_f32[M,2048] @ basis_bf16[256,2048]^T ----
// (unchanged from round 3 — verified)
__global__ __launch_bounds__(256) void gemm1_fused(const float* __restrict__ A,
                                                   const unsigned short* __restrict__ B,
                                                   unsigned short* __restrict__ C) {
    __shared__ float          Asm[2][32 * 64];    // 16 KB
    __shared__ unsigned short Bsm[2][256 * 64];   // 64 KB

    const int tid  = threadIdx.x;
    const int lane = tid & 63;
    const int wv   = tid >> 6;
    const int bm0  = blockIdx.x * 32;

    const float* srcA[2];
#pragma unroll
    for (int q = 0; q < 2; ++q) {
        int L = q * 256 + tid;
        int r = L >> 4, p = L & 15;
        int c = p ^ (r & 15);
        srcA[q] = A + (size_t)(bm0 + r) * K_IN + c * 4;
    }
    const unsigned short* srcB[8];
#pragma unroll
    for (int q = 0; q < 8; ++q) {
        int L = q * 256 + tid;
        int r = L >> 3, p = L & 7;
        int c = p ^ (r & 7);
        srcB[q] = B + (size_t)r * K_IN + c * 8;
    }
    const int dA = wv * 256 + lane * 4;   // floats, + q*1024
    const int dB = wv * 512 + lane * 8;   // shorts, + q*2048

    f32x16 acc[2];
#pragma unroll
    for (int nf = 0; nf < 2; ++nf)
#pragma unroll
        for (int e = 0; e < 16; ++e) acc[nf][e] = 0.f;

    const int r   = lane & 31;
    const int g   = lane >> 5;
    const int r15 = r & 15;
    const int colb = wv * 64;

#pragma unroll
    for (int q = 0; q < 2; ++q) GLDS(srcA[q], &Asm[0][q * 1024 + dA]);
#pragma unroll
    for (int q = 0; q < 8; ++q) GLDS(srcB[q], &Bsm[0][q * 2048 + dB]);
    __syncthreads();

    for (int t = 0; t < 32; ++t) {
        const int buf = t & 1;
        if (t + 1 < 32) {
            const int k0 = (t + 1) * 64;
#pragma unroll
            for (int q = 0; q < 2; ++q) GLDS(srcA[q] + k0, &Asm[buf ^ 1][q * 1024 + dA]);
#pragma unroll
            for (int q = 0; q < 8; ++q) GLDS(srcB[q] + k0, &Bsm[buf ^ 1][q * 2048 + dB]);
        }

        bf16x8 af[4];
#pragma unroll
        for (int ks = 0; ks < 4; ++ks) {
            const int c0 = g * 2 + ks * 4;
            f32x4 lo = *(const f32x4*)&Asm[buf][r * 64 + ((c0)     ^ r15) * 4];
            f32x4 hi = *(const f32x4*)&Asm[buf][r * 64 + ((c0 + 1) ^ r15) * 4];
            af[ks] = cvt8(lo, hi);
        }
#pragma unroll
        for (int nf = 0; nf < 2; ++nf) {
            const int rB = colb + nf * 32 + r;
            const int r7 = rB & 7;
#pragma unroll
            for (int ks = 0; ks < 4; ++ks) {
                const int cB = g + ks * 2;
                bf16x8 bfrag = *(const bf16x8*)&Bsm[buf][rB * 64 + (cB ^ r7) * 8];
                acc[nf] = __builtin_amdgcn_mfma_f32_32x32x16_bf16(af[ks], bfrag, acc[nf], 0, 0, 0);
            }
        }
        __syncthreads();
    }

#pragma unroll
    for (int nf = 0; nf < 2; ++nf)
#pragma unroll
        for (int reg = 0; reg < 16; ++reg) {
            int row = bm0 + (reg & 3) + 8 * (reg >> 2) + 4 * g;
            int col = colb + nf * 32 + r;
            C[(size_t)row * N_HARM + col] = f2bf(acc[nf][reg]);
        }
}

// ---- gemm2_pipe: out[M][8192] = rb[M][256] @ wreal[8192][256]^T ----
// 128x128 tile, BK=32, 4 waves (2x2 of 64x64, 2x2 frags of 32x32x16).
// 3 LDS buffers, depth-2 prefetch, counted vmcnt(4), raw s_barrier (1/iter).
// LDS layout per buffer: 64 LDS-rows x 64 shorts (128 B). Logical (m,k):
//   lrow=m&63, chunk=(m>>6)*4+(k>>3), elem=k&7, chunk^=(lrow&7).
// Staged with inverse-swizzled global source, linear GLDS dest.
__global__ __launch_bounds__(256) void gemm2_pipe(const unsigned short* __restrict__ A,
                                                  const unsigned short* __restrict__ B,
                                                  float* __restrict__ Cv) {
    __shared__ unsigned short As[3][4096];   // 8 KB x3
    __shared__ unsigned short Bs[3][4096];   // 8 KB x3

    const int tid  = threadIdx.x;
    const int lane = tid & 63;
    const int wv   = tid >> 6;
    const int wr   = wv >> 1;
    const int wc   = wv & 1;
    const int bm0  = blockIdx.y * 128;
    const int bn0  = blockIdx.x * 128;

    // staging sources: linear chunk L = q*256+tid -> lrow=L>>3, chunk'=L&7;
    // logical chunk = chunk' ^ (lrow&7); m=(chunk>>2)*64+lrow; k=(chunk&3)*8
    const unsigned short* srcA[2];
    const unsigned short* srcB[2];
#pragma unroll
    for (int q = 0; q < 2; ++q) {
        int L = q * 256 + tid;
        int lrow = L >> 3, chp = L & 7;
        int ch = chp ^ (lrow & 7);
        int m = (ch >> 2) * 64 + lrow;
        int k = (ch & 3) * 8;
        srcA[q] = A + (size_t)(bm0 + m) * N_HARM + k;
        srcB[q] = B + (size_t)(bn0 + m) * N_HARM + k;
    }
    const int dst = tid * 8;   // shorts; + q*2048

#define STAGE2(b, t) do { \
    GLDS(srcA[0] + (t) * 32, &As[b][dst]);        \
    GLDS(srcA[1] + (t) * 32, &As[b][2048 + dst]); \
    GLDS(srcB[0] + (t) * 32, &Bs[b][dst]);        \
    GLDS(srcB[1] + (t) * 32, &Bs[b][2048 + dst]); } while (0)

    f32x16 acc[2][2];
#pragma unroll
    for (int mi = 0; mi < 2; ++mi)
#pragma unroll
        for (int nj = 0; nj < 2; ++nj)
#pragma unroll
            for (int e = 0; e < 16; ++e) acc[mi][nj][e] = 0.f;

    const int r  = lane & 31;
    const int g  = lane >> 5;
    const int r7 = r & 7;

    // prologue: stage k-tiles 0 and 1 (8 loads outstanding)
    STAGE2(0, 0);
    STAGE2(1, 1);

#pragma unroll
    for (int t = 0; t < 8; ++t) {
        // wait for stage(t): outstanding = stage(t)+stage(t+1) = 8 -> <=4
        if (t == 7) { asm volatile("s_waitcnt vmcnt(0)" ::: "memory"); }
        else        { asm volatile("s_waitcnt vmcnt(4)" ::: "memory"); }
        __builtin_amdgcn_s_barrier();
        if (t + 2 < 8) STAGE2((t + 2) % 3, t + 2);

        const int b = t % 3;
        bf16x8 af[2][2], bfx[2][2];
#pragma unroll
        for (int mi = 0; mi < 2; ++mi)
#pragma unroll
            for (int ks = 0; ks < 2; ++ks) {
                af[mi][ks]  = *(const bf16x8*)&As[b][(mi * 32 + r) * 64 + ((wr * 4 + ks * 2 + g) ^ r7) * 8];
                bfx[mi][ks] = *(const bf16x8*)&Bs[b][(mi * 32 + r) * 64 + ((wc * 4 + ks * 2 + g) ^ r7) * 8];
            }
#pragma unroll
        for (int ks = 0; ks < 2; ++ks)
#pragma unroll
            for (int mi = 0; mi < 2; ++mi)
#pragma unroll
                for (int nj = 0; nj < 2; ++nj)
                    acc[mi][nj] = __builtin_amdgcn_mfma_f32_32x32x16_bf16(af[mi][ks], bfx[nj][ks], acc[mi][nj], 0, 0, 0);
    }
#undef STAGE2

    // C/D (32x32): col = lane&31, row = (reg&3) + 8*(reg>>2) + 4*(lane>>5)
#pragma unroll
    for (int mi = 0; mi < 2; ++mi)
#pragma unroll
        for (int nj = 0; nj < 2; ++nj)
#pragma unroll
            for (int reg = 0; reg < 16; ++reg) {
                int row = bm0 + wr * 64 + mi * 32 + (reg & 3) + 8 * (reg >> 2) + 4 * g;
                int col = bn0 + wc * 64 + nj * 32 + r;
                Cv[(size_t)row * N_OUT + col] = acc[mi][nj][reg];
            }
}

extern "C" void kernel_launch(void* const* d_in, const int* in_sizes, int n_in,
                              void* d_out, int out_size, void* d_ws, size_t ws_size,
                              hipStream_t stream) {
    const float* x     = (const float*)d_in[0];   // [4,4096,2048]
    const float* basis = (const float*)d_in[1];   // [256,2048]
    const float* phase = (const float*)d_in[2];   // [8192,256]
    const float* amp   = (const float*)d_in[3];   // [8192,256]
    float* out = (float*)d_out;                   // [4,4096,8192] fp32

    char* ws = (char*)d_ws;
    unsigned short* bb  = (unsigned short*)(ws);             // basis bf16: 1 MB
    unsigned short* wrb = (unsigned short*)(ws + 1048576);   // wreal bf16: 4 MB
    unsigned short* rb  = (unsigned short*)(ws + 5242880);   // resonance:  8 MB

    cvt_bf16<<<dim3(256), dim3(256), 0, stream>>>(basis, bb);
    wreal_bf16<<<dim3(1024), dim3(256), 0, stream>>>(phase, amp, wrb);

    // resonance[16384,256] = x @ bb^T  (fp32 A staged to LDS, fused cvt)
    gemm1_fused<<<dim3(M_ROWS / 32), dim3(256), 0, stream>>>(x, bb, rb);
    // out[16384,8192] = rb @ wrb^T  (depth-2 counted-vmcnt pipeline)
    gemm2_pipe<<<dim3(N_OUT / 128, M_ROWS / 128), dim3(256), 0, stream>>>(rb, wrb, out);
}